// Round 1
// baseline (1300.028 us; speedup 1.0000x reference)
//
#include <hip/hip_runtime.h>
#include <hip/hip_bf16.h>
#include <cstdint>
#include <cstddef>

// ---------------- graph structure ----------------

__global__ void k_deg_hist(const int* __restrict__ dst, int* __restrict__ deg, int E){
  int i = blockIdx.x*blockDim.x + threadIdx.x;
  int stride = gridDim.x*blockDim.x;
  for(; i<E; i+=stride) atomicAdd(&deg[dst[i]], 1);
}

__global__ void k_batch_hist(const int* __restrict__ batch, int* __restrict__ cnt, int n){
  __shared__ int h[64];
  if(threadIdx.x<64) h[threadIdx.x]=0;
  __syncthreads();
  int i = blockIdx.x*blockDim.x + threadIdx.x;
  int stride = gridDim.x*blockDim.x;
  for(; i<n; i+=stride) atomicAdd(&h[batch[i]], 1);
  __syncthreads();
  if(threadIdx.x<64 && h[threadIdx.x]) atomicAdd(&cnt[threadIdx.x], h[threadIdx.x]);
}

__global__ void k_dinv(const int* __restrict__ deg, float* __restrict__ dinv, int n){
  int i = blockIdx.x*blockDim.x + threadIdx.x;
  if(i<n) dinv[i] = rsqrtf((float)(deg[i]+1));   // +1 = self loop
}

__global__ void k_scan1(const int* __restrict__ deg, int* __restrict__ bsum, int n){
  __shared__ int s[256];
  int base = blockIdx.x*1024 + threadIdx.x*4;
  int acc=0;
  #pragma unroll
  for(int j=0;j<4;j++){ int i=base+j; if(i<n) acc+=deg[i]; }
  s[threadIdx.x]=acc; __syncthreads();
  for(int off=128;off>0;off>>=1){
    if(threadIdx.x<off) s[threadIdx.x]+=s[threadIdx.x+off];
    __syncthreads();
  }
  if(threadIdx.x==0) bsum[blockIdx.x]=s[0];
}

__global__ void k_scan2(int* __restrict__ bsum, int nblk, int* __restrict__ rowptr, int n){
  __shared__ int s[128];
  int t=threadIdx.x;
  int v = (t<nblk)? bsum[t] : 0;
  s[t]=v; __syncthreads();
  for(int off=1; off<128; off<<=1){
    int a = (t>=off)? s[t-off] : 0;
    __syncthreads();
    s[t]+=a;
    __syncthreads();
  }
  if(t<nblk) bsum[t]=s[t]-v;         // exclusive block offsets
  if(t==127) rowptr[n]=s[127];       // total = E
}

__global__ void k_scan3(const int* __restrict__ deg, const int* __restrict__ bsum,
                        int* __restrict__ rowptr, int* __restrict__ cursor, int n){
  __shared__ int s[256];
  int base = blockIdx.x*1024 + threadIdx.x*4;
  int v[4]; int acc=0;
  #pragma unroll
  for(int j=0;j<4;j++){ int i=base+j; v[j]=(i<n)?deg[i]:0; acc+=v[j]; }
  s[threadIdx.x]=acc; __syncthreads();
  for(int off=1; off<256; off<<=1){
    int a = (threadIdx.x>=off)? s[threadIdx.x-off] : 0;
    __syncthreads();
    s[threadIdx.x]+=a;
    __syncthreads();
  }
  int excl = s[threadIdx.x]-acc + bsum[blockIdx.x];
  #pragma unroll
  for(int j=0;j<4;j++){
    int i=base+j;
    if(i<n){ rowptr[i]=excl; cursor[i]=excl; excl+=v[j]; }
  }
}

__global__ void k_csr_fill(const int* __restrict__ src, const int* __restrict__ dst,
                           int* __restrict__ cursor, int* __restrict__ adj, int E){
  int e = blockIdx.x*blockDim.x + threadIdx.x;
  if(e<E){
    int p = atomicAdd(&cursor[dst[e]], 1);
    adj[p] = src[e];
  }
}

// ---------------- GCN pieces ----------------

// out[node][c4] = in[node][c4] * dinv[node]   (float4 granularity, C=F/4 chunks, lgC=log2(C))
__global__ void k_rowscale(const float* __restrict__ in, const float* __restrict__ dinv,
                           float* __restrict__ out, int n, int lgC){
  int tid = blockIdx.x*blockDim.x + threadIdx.x;
  int node = tid >> lgC;
  if(node>=n) return;
  int c4 = tid & ((1<<lgC)-1);
  size_t idx = ((size_t)node<<lgC) + c4;
  float4 v = ((const float4*)in)[idx];
  float d = dinv[node];
  v.x*=d; v.y*=d; v.z*=d; v.w*=d;
  ((float4*)out)[idx] = v;
}

// out[i] = dinv[i] * (sum_{e:dst=i} zs[adj[e]] + zs[i]) + bias
__global__ void k_aggregate(const float* __restrict__ zs, const int* __restrict__ rowptr,
                            const int* __restrict__ adj, const float* __restrict__ dinv,
                            const float* __restrict__ bias, float* __restrict__ out,
                            int n, int lgC){
  int tid = blockIdx.x*blockDim.x + threadIdx.x;
  int node = tid >> lgC;
  if(node>=n) return;
  int C = 1<<lgC;
  int c4 = tid & (C-1);
  const float4* z4 = (const float4*)zs;
  size_t rb = ((size_t)node<<lgC) + c4;
  float4 a0 = z4[rb];                       // self-loop term (zs already *dinv)
  float4 a1 = make_float4(0.f,0.f,0.f,0.f);
  int e = rowptr[node], end = rowptr[node+1];
  for(; e+1<end; e+=2){
    int s0=adj[e], s1=adj[e+1];
    float4 v0 = z4[((size_t)s0<<lgC)+c4];
    float4 v1 = z4[((size_t)s1<<lgC)+c4];
    a0.x+=v0.x; a0.y+=v0.y; a0.z+=v0.z; a0.w+=v0.w;
    a1.x+=v1.x; a1.y+=v1.y; a1.z+=v1.z; a1.w+=v1.w;
  }
  if(e<end){
    int s0=adj[e];
    float4 v0 = z4[((size_t)s0<<lgC)+c4];
    a0.x+=v0.x; a0.y+=v0.y; a0.z+=v0.z; a0.w+=v0.w;
  }
  a0.x+=a1.x; a0.y+=a1.y; a0.z+=a1.z; a0.w+=a1.w;
  float di = dinv[node];
  a0.x*=di; a0.y*=di; a0.z*=di; a0.w*=di;
  if(bias){
    int c = c4<<2;
    a0.x+=bias[c]; a0.y+=bias[c+1]; a0.z+=bias[c+2]; a0.w+=bias[c+3];
  }
  ((float4*)out)[rb] = a0;
}

// C[n,F] = A[n,K] @ W[K,F]  (+bias[F]) (* rscale[row]); F = 16*FC
template<int FC>
__global__ __launch_bounds__(256) void k_gemm(const float* __restrict__ A, const float* __restrict__ W,
                                              const float* __restrict__ bias, const float* __restrict__ rscale,
                                              float* __restrict__ C, int n, int K){
  constexpr int F = 16*FC;
  __shared__ float sW[32*F];
  __shared__ float sX[64*33];
  const int tid = threadIdx.x;
  const int tr = tid>>4, tc = tid&15;
  const int row0 = blockIdx.x<<6;
  float acc[4][FC];
  #pragma unroll
  for(int i=0;i<4;i++)
    #pragma unroll
    for(int j=0;j<FC;j++) acc[i][j]=0.f;
  for(int k0=0;k0<K;k0+=32){
    __syncthreads();
    #pragma unroll
    for(int idx=tid; idx<32*F; idx+=256) sW[idx] = W[(size_t)(k0 + idx/F)*F + (idx%F)];
    #pragma unroll
    for(int idx=tid; idx<64*32; idx+=256){
      int r = idx>>5, kk = idx&31;
      sX[r*33+kk] = A[(size_t)(row0+r)*K + k0+kk];   // A's buffer is never last in ws -> safe tail overread
    }
    __syncthreads();
    #pragma unroll 8
    for(int kk=0;kk<32;kk++){
      float a[4];
      #pragma unroll
      for(int i=0;i<4;i++) a[i] = sX[(tr*4+i)*33 + kk];
      #pragma unroll
      for(int j=0;j<FC;j++){
        float bw = sW[kk*F + tc + (j<<4)];           // stride-16 cols: conflict-free b32 broadcasts
        #pragma unroll
        for(int i=0;i<4;i++) acc[i][j] = fmaf(a[i], bw, acc[i][j]);
      }
    }
  }
  #pragma unroll
  for(int i=0;i<4;i++){
    int row = row0 + tr*4 + i;
    if(row < n){
      float sc = rscale ? rscale[row] : 1.f;
      #pragma unroll
      for(int j=0;j<FC;j++){
        int c = tc + (j<<4);
        float v = acc[i][j]*sc;
        if(bias) v += bias[c];
        C[(size_t)row*F + c] = v;
      }
    }
  }
}

// ---------------- BatchNorm ----------------

__global__ void k_bn_stats(const float* __restrict__ h, float* __restrict__ sums,
                           float* __restrict__ sumsq, int n, int lgF){
  int F = 1<<lgF;
  int f = threadIdx.x & (F-1);
  int sub = threadIdx.x >> lgF;
  int rpb = 256 >> lgF;
  int row = blockIdx.x*rpb + sub;
  int stride = gridDim.x*rpb;
  float s=0.f, s2=0.f;
  for(; row<n; row+=stride){
    float v = h[((size_t)row<<lgF) + f];
    s += v; s2 = fmaf(v,v,s2);
  }
  atomicAdd(&sums[f], s);
  atomicAdd(&sumsq[f], s2);
}

__global__ void k_bn_finalize(const float* __restrict__ sums, const float* __restrict__ sumsq,
                              const float* __restrict__ g, const float* __restrict__ be,
                              float* __restrict__ scale, float* __restrict__ shift, int n, int F){
  int f = threadIdx.x;
  if(f<F){
    float mu = sums[f]/(float)n;
    float var = sumsq[f]/(float)n - mu*mu;
    float sc = g[f]*rsqrtf(var+1e-5f);
    scale[f] = sc;
    shift[f] = fmaf(-mu, sc, be[f]);
  }
}

__global__ void k_bn_apply(float* __restrict__ h, const float* __restrict__ scale,
                           const float* __restrict__ shift, int n, int lgF){
  size_t i = (size_t)blockIdx.x*256 + threadIdx.x;    // float4 index
  size_t total = ((size_t)n << lgF) >> 2;
  if(i>=total) return;
  int c = (int)((i<<2) & ((size_t)(1<<lgF)-1));
  float4 v = ((const float4*)h)[i];
  v.x = fmaxf(fmaf(v.x,scale[c  ],shift[c  ]),0.f);
  v.y = fmaxf(fmaf(v.y,scale[c+1],shift[c+1]),0.f);
  v.z = fmaxf(fmaf(v.z,scale[c+2],shift[c+2]),0.f);
  v.w = fmaxf(fmaf(v.w,scale[c+3],shift[c+3]),0.f);
  ((float4*)h)[i] = v;
}

// ---------------- head: LN + attention + pool + MLP ----------------

__global__ void k_ln_att(const float* __restrict__ x, const float* __restrict__ g, const float* __restrict__ b,
                         const float* __restrict__ att, float* __restrict__ lnx, float* __restrict__ wv,
                         float* __restrict__ Ssum, int n){
  int lane = threadIdx.x & 63;
  int wid = (blockIdx.x<<2) + (threadIdx.x>>6);
  float gl=g[lane], bl=b[lane], al=att[lane];
  float wacc=0.f;
  for(int node=wid; node<n; node+=4096){
    float v = x[((size_t)node<<6)+lane];
    float s=v;
    #pragma unroll
    for(int o=32;o>0;o>>=1) s += __shfl_xor(s,o);
    float mu = s*0.015625f;
    float d = v-mu;
    float q = d*d;
    #pragma unroll
    for(int o=32;o>0;o>>=1) q += __shfl_xor(q,o);
    float ln = d*rsqrtf(q*0.015625f + 1e-5f)*gl + bl;
    lnx[((size_t)node<<6)+lane] = ln;
    float a = ln*al;
    #pragma unroll
    for(int o=32;o>0;o>>=1) a += __shfl_xor(a,o);
    float w = expf(tanhf(a));       // softmax w/o max-sub: tanh in [-1,1], stable
    if(lane==0) wv[node]=w;
    wacc += w;
  }
  __shared__ float sred[4];
  if(lane==0) sred[threadIdx.x>>6]=wacc;
  __syncthreads();
  if(threadIdx.x==0) atomicAdd(Ssum, sred[0]+sred[1]+sred[2]+sred[3]);
}

__global__ void k_pool(const float* __restrict__ lnx, const float* __restrict__ wv,
                       const int* __restrict__ batch, float* __restrict__ psum, int n){
  int lane = threadIdx.x & 63;
  int wave = threadIdx.x >> 6;
  int start = blockIdx.x*512 + wave*128;
  if(start >= n) return;                 // wave-uniform
  int end = min(start+128, n);
  int cur = batch[start];
  float acc = 0.f;
  for(int i=start;i<end;i++){
    int bb = batch[i];                   // sorted -> wave-uniform broadcast
    if(bb != cur){ atomicAdd(&psum[cur*64+lane], acc); acc=0.f; cur=bb; }
    acc = fmaf(lnx[(size_t)i*64+lane], wv[i], acc);
  }
  atomicAdd(&psum[cur*64+lane], acc);
}

__global__ void k_mlp(const float* __restrict__ psum, const int* __restrict__ cnt,
                      const float* __restrict__ Ssum,
                      const float* __restrict__ M0W, const float* __restrict__ M0b,
                      const float* __restrict__ M1W, const float* __restrict__ M1b,
                      const float* __restrict__ M2W, const float* __restrict__ M2b,
                      float* __restrict__ out){
  int b = threadIdx.x;                   // 64 graphs, 1 wave
  float S = Ssum[0];
  int cb = cnt[b]; if(cb<1) cb=1;
  float inv = 1.f/(S*(float)cb);
  float p[64];
  #pragma unroll
  for(int f=0;f<64;f++) p[f] = psum[b*64+f]*inv;
  float h1[32];
  #pragma unroll
  for(int j=0;j<32;j++){
    float a=M0b[j];
    #pragma unroll
    for(int f=0;f<64;f++) a = fmaf(p[f], M0W[f*32+j], a);
    h1[j]=fmaxf(a,0.f);
  }
  float h2[16];
  #pragma unroll
  for(int j=0;j<16;j++){
    float a=M1b[j];
    #pragma unroll
    for(int f=0;f<32;f++) a = fmaf(h1[f], M1W[f*16+j], a);
    h2[j]=fmaxf(a,0.f);
  }
  #pragma unroll
  for(int j=0;j<2;j++){
    float a=M2b[j];
    #pragma unroll
    for(int f=0;f<16;f++) a = fmaf(h2[f], M2W[f*2+j], a);
    out[b*2+j]=a;
  }
}

// ---------------- launch ----------------

extern "C" void kernel_launch(void* const* d_in, const int* in_sizes, int n_in,
                              void* d_out, int out_size, void* d_ws, size_t ws_size,
                              hipStream_t stream){
  const float* x   = (const float*)d_in[0];
  const int*   ei  = (const int*)d_in[1];
  const int* batch = (const int*)d_in[2];
  const float* W0=(const float*)d_in[3],  *b0=(const float*)d_in[4],  *g0=(const float*)d_in[5],  *be0=(const float*)d_in[6];
  const float* W1=(const float*)d_in[7],  *b1=(const float*)d_in[8],  *g1=(const float*)d_in[9],  *be1=(const float*)d_in[10];
  const float* W2=(const float*)d_in[11], *b2=(const float*)d_in[12], *g2=(const float*)d_in[13], *be2=(const float*)d_in[14];
  const float* ln_g=(const float*)d_in[15], *ln_b=(const float*)d_in[16], *att=(const float*)d_in[17];
  const float* M0W=(const float*)d_in[18], *M0b=(const float*)d_in[19];
  const float* M1W=(const float*)d_in[20], *M1b=(const float*)d_in[21];
  const float* M2W=(const float*)d_in[22], *M2b=(const float*)d_in[23];
  const int N = in_sizes[0]/128;
  const int E = in_sizes[1]/2;
  const int* srcv = ei;
  const int* dstv = ei + E;

  char* base = (char*)d_ws;
  size_t off = 0;
  auto alloc = [&](size_t bytes)->char*{ char* p = base+off; off = (off+bytes+255)&~(size_t)255; return p; };
  // zeroed region first
  int*   deg    = (int*)  alloc((size_t)N*4);
  int*   cnt    = (int*)  alloc(64*4);
  float* stats  = (float*)alloc(6*256*4);
  float* psum   = (float*)alloc(64*64*4);
  float* Ssum   = (float*)alloc(4);
  size_t zero_bytes = off;
  float* dinv   = (float*)alloc((size_t)N*4);
  int*   rowptr = (int*)  alloc(((size_t)N+1)*4);
  int*   cursor = (int*)  alloc((size_t)N*4);
  int*   bsum   = (int*)  alloc(128*4);
  float* bnsc   = (float*)alloc(3*256*4);
  float* bnsh   = (float*)alloc(3*256*4);
  int*   adj    = (int*)  alloc((size_t)E*4);
  float* P      = (float*)alloc((size_t)N*256*4);   // [N,256]
  float* R      = (float*)alloc((size_t)N*128*4);   // [N,128]
  float* Q      = (float*)alloc((size_t)N*128*4);   // [N,128] (last: only guarded writes / in-bounds reads)
  (void)ws_size; (void)n_in; (void)out_size;

  hipMemsetAsync(d_ws, 0, zero_bytes, stream);

  // graph structure (shared by all 3 layers)
  k_deg_hist  <<<1024,256,0,stream>>>(dstv, deg, E);
  k_batch_hist<<<256,256,0,stream>>>(batch, cnt, N);
  k_dinv      <<<(N+255)/256,256,0,stream>>>(deg, dinv, N);
  int nblk = (N+1023)/1024;
  k_scan1<<<nblk,256,0,stream>>>(deg, bsum, N);
  k_scan2<<<1,128,0,stream>>>(bsum, nblk, rowptr, N);
  k_scan3<<<nblk,256,0,stream>>>(deg, bsum, rowptr, cursor, N);
  k_csr_fill<<<(E+255)/256,256,0,stream>>>(srcv, dstv, cursor, adj, E);

  // ---- layer 0: aggregate(x) @ W0 + b0, BN, relu ----
  k_rowscale <<<(N*32+255)/256,256,0,stream>>>(x, dinv, Q, N, 5);
  k_aggregate<<<(N*32+255)/256,256,0,stream>>>(Q, rowptr, adj, dinv, nullptr, R, N, 5);
  k_gemm<16> <<<(N+63)/64,256,0,stream>>>(R, W0, b0, nullptr, P, N, 128);
  k_bn_stats <<<256,256,0,stream>>>(P, stats+0, stats+256, N, 8);
  k_bn_finalize<<<1,256,0,stream>>>(stats+0, stats+256, g0, be0, bnsc+0, bnsh+0, N, 256);
  k_bn_apply <<<(N*64+255)/256,256,0,stream>>>(P, bnsc+0, bnsh+0, N, 8);

  // ---- layer 1: aggregate(x1 @ W1) + b1, BN, relu ----
  k_gemm<8>  <<<(N+63)/64,256,0,stream>>>(P, W1, nullptr, dinv, Q, N, 256);
  k_aggregate<<<(N*32+255)/256,256,0,stream>>>(Q, rowptr, adj, dinv, b1, R, N, 5);
  k_bn_stats <<<256,256,0,stream>>>(R, stats+512, stats+768, N, 7);
  k_bn_finalize<<<1,256,0,stream>>>(stats+512, stats+768, g1, be1, bnsc+256, bnsh+256, N, 128);
  k_bn_apply <<<(N*32+255)/256,256,0,stream>>>(R, bnsc+256, bnsh+256, N, 7);

  // ---- layer 2 ----
  k_gemm<4>  <<<(N+63)/64,256,0,stream>>>(R, W2, nullptr, dinv, Q, N, 128);
  k_aggregate<<<(N*16+255)/256,256,0,stream>>>(Q, rowptr, adj, dinv, b2, P, N, 4);
  k_bn_stats <<<256,256,0,stream>>>(P, stats+1024, stats+1280, N, 6);
  k_bn_finalize<<<1,256,0,stream>>>(stats+1024, stats+1280, g2, be2, bnsc+512, bnsh+512, N, 64);
  k_bn_apply <<<(N*16+255)/256,256,0,stream>>>(P, bnsc+512, bnsh+512, N, 6);

  // ---- head ----
  k_ln_att<<<1024,256,0,stream>>>(P, ln_g, ln_b, att, Q, R, Ssum, N);
  k_pool  <<<(N+511)/512,256,0,stream>>>(Q, R, batch, psum, N);
  k_mlp   <<<1,64,0,stream>>>(psum, cnt, Ssum, M0W,M0b,M1W,M1b,M2W,M2b, (float*)d_out);
}

// Round 2
// 1045.800 us; speedup vs baseline: 1.2431x; 1.2431x over previous
//
#include <hip/hip_runtime.h>
#include <hip/hip_bf16.h>
#include <cstdint>
#include <cstddef>

typedef float  f32x4  __attribute__((ext_vector_type(4)));
typedef __bf16 bf16x8 __attribute__((ext_vector_type(8)));

__device__ __forceinline__ unsigned short f2bf(float x){
  unsigned u = __float_as_uint(x);
  return (unsigned short)((u + 0x7fffu + ((u >> 16) & 1u)) >> 16);
}
__device__ __forceinline__ float bfhi(unsigned short h){
  return __uint_as_float(((unsigned)h) << 16);
}

// ---------------- graph structure ----------------

__global__ void k_deg_hist(const int* __restrict__ dst, int* __restrict__ deg, int E){
  int i = blockIdx.x*blockDim.x + threadIdx.x;
  int stride = gridDim.x*blockDim.x;
  for(; i<E; i+=stride) atomicAdd(&deg[dst[i]], 1);
}

__global__ void k_batch_hist(const int* __restrict__ batch, int* __restrict__ cnt, int n){
  __shared__ int h[64];
  if(threadIdx.x<64) h[threadIdx.x]=0;
  __syncthreads();
  int i = blockIdx.x*blockDim.x + threadIdx.x;
  int stride = gridDim.x*blockDim.x;
  for(; i<n; i+=stride) atomicAdd(&h[batch[i]], 1);
  __syncthreads();
  if(threadIdx.x<64 && h[threadIdx.x]) atomicAdd(&cnt[threadIdx.x], h[threadIdx.x]);
}

__global__ void k_dinv(const int* __restrict__ deg, float* __restrict__ dinv, int n){
  int i = blockIdx.x*blockDim.x + threadIdx.x;
  if(i<n) dinv[i] = rsqrtf((float)(deg[i]+1));   // +1 = self loop
}

__global__ void k_scan1(const int* __restrict__ deg, int* __restrict__ bsum, int n){
  __shared__ int s[256];
  int base = blockIdx.x*1024 + threadIdx.x*4;
  int acc=0;
  #pragma unroll
  for(int j=0;j<4;j++){ int i=base+j; if(i<n) acc+=deg[i]; }
  s[threadIdx.x]=acc; __syncthreads();
  for(int off=128;off>0;off>>=1){
    if(threadIdx.x<off) s[threadIdx.x]+=s[threadIdx.x+off];
    __syncthreads();
  }
  if(threadIdx.x==0) bsum[blockIdx.x]=s[0];
}

__global__ void k_scan2(int* __restrict__ bsum, int nblk, int* __restrict__ rowptr, int n){
  __shared__ int s[128];
  int t=threadIdx.x;
  int v = (t<nblk)? bsum[t] : 0;
  s[t]=v; __syncthreads();
  for(int off=1; off<128; off<<=1){
    int a = (t>=off)? s[t-off] : 0;
    __syncthreads();
    s[t]+=a;
    __syncthreads();
  }
  if(t<nblk) bsum[t]=s[t]-v;         // exclusive block offsets
  if(t==127) rowptr[n]=s[127];       // total = E
}

__global__ void k_scan3(const int* __restrict__ deg, const int* __restrict__ bsum,
                        int* __restrict__ rowptr, int* __restrict__ cursor, int n){
  __shared__ int s[256];
  int base = blockIdx.x*1024 + threadIdx.x*4;
  int v[4]; int acc=0;
  #pragma unroll
  for(int j=0;j<4;j++){ int i=base+j; v[j]=(i<n)?deg[i]:0; acc+=v[j]; }
  s[threadIdx.x]=acc; __syncthreads();
  for(int off=1; off<256; off<<=1){
    int a = (threadIdx.x>=off)? s[threadIdx.x-off] : 0;
    __syncthreads();
    s[threadIdx.x]+=a;
    __syncthreads();
  }
  int excl = s[threadIdx.x]-acc + bsum[blockIdx.x];
  #pragma unroll
  for(int j=0;j<4;j++){
    int i=base+j;
    if(i<n){ rowptr[i]=excl; cursor[i]=excl; excl+=v[j]; }
  }
}

__global__ void k_csr_fill(const int* __restrict__ src, const int* __restrict__ dst,
                           int* __restrict__ cursor, int* __restrict__ adj, int E){
  int e = blockIdx.x*blockDim.x + threadIdx.x;
  if(e<E){
    int p = atomicAdd(&cursor[dst[e]], 1);
    adj[p] = src[e];
  }
}

// ---------------- W preprocess: transpose + bf16 hi/lo split ----------------

__global__ void k_prep_w(const float* __restrict__ W, unsigned short* __restrict__ Wh,
                         unsigned short* __restrict__ Wl, int K, int F){
  int i = blockIdx.x*256 + threadIdx.x;
  if(i < K*F){
    int k = i / F, f = i % F;
    float a = W[i];
    unsigned short h = f2bf(a);
    Wh[(size_t)f*K + k] = h;
    Wl[(size_t)f*K + k] = f2bf(a - bfhi(h));
  }
}

// ---------------- aggregate ----------------
// out[i] = dinv[i] * ( sum_{e:dst=i} zs[src]*(SS?dinv[src]:1) + zs[i]*(SS?dinv[i]:1) ) + bias
template<bool SS>
__global__ void k_aggregate(const float* __restrict__ zs, const int* __restrict__ rowptr,
                            const int* __restrict__ adj, const float* __restrict__ dinv,
                            const float* __restrict__ bias, float* __restrict__ out,
                            int n, int lgC){
  int tid = blockIdx.x*blockDim.x + threadIdx.x;
  int node = tid >> lgC;
  if(node>=n) return;
  int C = 1<<lgC;
  int c4 = tid & (C-1);
  const float4* z4 = (const float4*)zs;
  size_t rb = ((size_t)node<<lgC) + c4;
  float4 a0 = z4[rb];
  if(SS){ float d=dinv[node]; a0.x*=d; a0.y*=d; a0.z*=d; a0.w*=d; }
  float4 a1 = make_float4(0.f,0.f,0.f,0.f);
  int e = rowptr[node], end = rowptr[node+1];
  for(; e+1<end; e+=2){
    int s0=adj[e], s1=adj[e+1];
    float4 v0 = z4[((size_t)s0<<lgC)+c4];
    float4 v1 = z4[((size_t)s1<<lgC)+c4];
    if(SS){
      float d0=dinv[s0], d1=dinv[s1];
      a0.x=fmaf(v0.x,d0,a0.x); a0.y=fmaf(v0.y,d0,a0.y); a0.z=fmaf(v0.z,d0,a0.z); a0.w=fmaf(v0.w,d0,a0.w);
      a1.x=fmaf(v1.x,d1,a1.x); a1.y=fmaf(v1.y,d1,a1.y); a1.z=fmaf(v1.z,d1,a1.z); a1.w=fmaf(v1.w,d1,a1.w);
    }else{
      a0.x+=v0.x; a0.y+=v0.y; a0.z+=v0.z; a0.w+=v0.w;
      a1.x+=v1.x; a1.y+=v1.y; a1.z+=v1.z; a1.w+=v1.w;
    }
  }
  if(e<end){
    int s0=adj[e];
    float4 v0 = z4[((size_t)s0<<lgC)+c4];
    if(SS){
      float d0=dinv[s0];
      a0.x=fmaf(v0.x,d0,a0.x); a0.y=fmaf(v0.y,d0,a0.y); a0.z=fmaf(v0.z,d0,a0.z); a0.w=fmaf(v0.w,d0,a0.w);
    }else{
      a0.x+=v0.x; a0.y+=v0.y; a0.z+=v0.z; a0.w+=v0.w;
    }
  }
  a0.x+=a1.x; a0.y+=a1.y; a0.z+=a1.z; a0.w+=a1.w;
  float di = dinv[node];
  a0.x*=di; a0.y*=di; a0.z*=di; a0.w*=di;
  if(bias){
    int c = c4<<2;
    a0.x+=bias[c]; a0.y+=bias[c+1]; a0.z+=bias[c+2]; a0.w+=bias[c+3];
  }
  ((float4*)out)[rb] = a0;
}

// ---------------- MFMA GEMM with bf16 hi/lo split ----------------
// C[n,F] = act(A[n,K]) @ W[K,F]; act = BN? relu(A*sc+sh) : A
// W given pre-transposed/split: Bh/Bl = bf16 [F][K].
// Epilogue: +bias[col] (BIAS), *rsc[row] (RSC).
template<int K, int F, bool BN, bool BIAS, bool RSC>
__global__ __launch_bounds__(256,2) void k_gemm_mfma(const float* __restrict__ A,
    const unsigned short* __restrict__ Bh, const unsigned short* __restrict__ Bl,
    const float* __restrict__ sc, const float* __restrict__ sh,
    const float* __restrict__ bias, const float* __restrict__ rsc,
    float* __restrict__ C, int n){
  constexpr int NF = F/16;
  const int l   = threadIdx.x & 63;
  const int w   = threadIdx.x >> 6;
  const int rlo = l & 15;            // A row within frag / C col within frag
  const int khi = l >> 4;            // k-group (0..3)
  const int row0 = blockIdx.x*128 + w*32;

  f32x4 acc[2][NF];
  #pragma unroll
  for(int i=0;i<2;i++)
    #pragma unroll
    for(int j=0;j<NF;j++) acc[i][j] = (f32x4){0.f,0.f,0.f,0.f};

  const float4* A4 = (const float4*)A;
  size_t ra0 = (size_t)min(row0 + rlo,      n-1) * (K/4);
  size_t ra1 = (size_t)min(row0 + 16 + rlo, n-1) * (K/4);
  const int kv = khi*2;   // float4 offset of this lane's 8-elem k-chunk

  float4 c00 = A4[ra0 + kv], c01 = A4[ra0 + kv + 1];
  float4 c10 = A4[ra1 + kv], c11 = A4[ra1 + kv + 1];

  #pragma unroll 1
  for(int k0=0; k0<K; k0+=32){
    float4 n00,n01,n10,n11;
    if(k0+32 < K){
      int kb = (k0+32)>>2;
      n00 = A4[ra0 + kb + kv]; n01 = A4[ra0 + kb + kv + 1];
      n10 = A4[ra1 + kb + kv]; n11 = A4[ra1 + kb + kv + 1];
    }
    float scr[8], shr[8];
    if(BN){
      float4 s0 = *(const float4*)(sc + k0 + khi*8);
      float4 s1 = *(const float4*)(sc + k0 + khi*8 + 4);
      float4 t0 = *(const float4*)(sh + k0 + khi*8);
      float4 t1 = *(const float4*)(sh + k0 + khi*8 + 4);
      scr[0]=s0.x;scr[1]=s0.y;scr[2]=s0.z;scr[3]=s0.w;scr[4]=s1.x;scr[5]=s1.y;scr[6]=s1.z;scr[7]=s1.w;
      shr[0]=t0.x;shr[1]=t0.y;shr[2]=t0.z;shr[3]=t0.w;shr[4]=t1.x;shr[5]=t1.y;shr[6]=t1.z;shr[7]=t1.w;
    }
    // convert this K-step's A fragments (fp32 -> bf16 hi/lo), optional BN+relu
    union { unsigned short u[8]; bf16x8 v; } H0,L0,H1,L1;
    {
      float v0[8] = {c00.x,c00.y,c00.z,c00.w,c01.x,c01.y,c01.z,c01.w};
      float v1[8] = {c10.x,c10.y,c10.z,c10.w,c11.x,c11.y,c11.z,c11.w};
      #pragma unroll
      for(int j=0;j<8;j++){
        float x0 = v0[j], x1 = v1[j];
        if(BN){ x0 = fmaxf(fmaf(x0,scr[j],shr[j]),0.f); x1 = fmaxf(fmaf(x1,scr[j],shr[j]),0.f); }
        unsigned short h0 = f2bf(x0), h1 = f2bf(x1);
        H0.u[j]=h0; L0.u[j]=f2bf(x0 - bfhi(h0));
        H1.u[j]=h1; L1.u[j]=f2bf(x1 - bfhi(h1));
      }
    }
    bf16x8 ah0=H0.v, al0=L0.v, ah1=H1.v, al1=L1.v;
    #pragma unroll
    for(int cf=0; cf<NF; cf++){
      size_t boff = (size_t)(cf*16 + rlo)*K + k0 + khi*8;
      bf16x8 bh = *(const bf16x8*)(Bh + boff);
      bf16x8 bl = *(const bf16x8*)(Bl + boff);
      acc[0][cf] = __builtin_amdgcn_mfma_f32_16x16x32_bf16(ah0, bh, acc[0][cf], 0,0,0);
      acc[1][cf] = __builtin_amdgcn_mfma_f32_16x16x32_bf16(ah1, bh, acc[1][cf], 0,0,0);
      acc[0][cf] = __builtin_amdgcn_mfma_f32_16x16x32_bf16(al0, bh, acc[0][cf], 0,0,0);
      acc[1][cf] = __builtin_amdgcn_mfma_f32_16x16x32_bf16(al1, bh, acc[1][cf], 0,0,0);
      acc[0][cf] = __builtin_amdgcn_mfma_f32_16x16x32_bf16(ah0, bl, acc[0][cf], 0,0,0);
      acc[1][cf] = __builtin_amdgcn_mfma_f32_16x16x32_bf16(ah1, bl, acc[1][cf], 0,0,0);
    }
    c00=n00; c01=n01; c10=n10; c11=n11;
  }

  // epilogue: C/D layout col=lane&15 (+16cf), row=(lane>>4)*4+reg (+16rf)
  #pragma unroll
  for(int rf=0; rf<2; rf++){
    #pragma unroll
    for(int r=0; r<4; r++){
      int m = row0 + rf*16 + khi*4 + r;
      if(m < n){
        float rs = RSC ? rsc[m] : 1.f;
        #pragma unroll
        for(int cf=0; cf<NF; cf++){
          int col = rlo + 16*cf;
          float v = acc[rf][cf][r];
          if(BIAS) v += bias[col];
          v *= rs;
          C[(size_t)m*F + col] = v;
        }
      }
    }
  }
}

// ---------------- BatchNorm stats ----------------

__global__ void k_bn_stats(const float* __restrict__ h, float* __restrict__ sums,
                           float* __restrict__ sumsq, int n, int lgF){
  int F = 1<<lgF;
  int f = threadIdx.x & (F-1);
  int sub = threadIdx.x >> lgF;
  int rpb = 256 >> lgF;
  int row = blockIdx.x*rpb + sub;
  int stride = gridDim.x*rpb;
  float s=0.f, s2=0.f;
  for(; row<n; row+=stride){
    float v = h[((size_t)row<<lgF) + f];
    s += v; s2 = fmaf(v,v,s2);
  }
  atomicAdd(&sums[f], s);
  atomicAdd(&sumsq[f], s2);
}

__global__ void k_bn_finalize(const float* __restrict__ sums, const float* __restrict__ sumsq,
                              const float* __restrict__ g, const float* __restrict__ be,
                              float* __restrict__ scale, float* __restrict__ shift, int n, int F){
  int f = threadIdx.x;
  if(f<F){
    float mu = sums[f]/(float)n;
    float var = sumsq[f]/(float)n - mu*mu;
    float sc = g[f]*rsqrtf(var+1e-5f);
    scale[f] = sc;
    shift[f] = fmaf(-mu, sc, be[f]);
  }
}

// ---------------- head: (BN2+relu) + LN + attention + pool + MLP ----------------

__global__ void k_ln_att(const float* __restrict__ x, const float* __restrict__ bsc, const float* __restrict__ bsh,
                         const float* __restrict__ g, const float* __restrict__ b,
                         const float* __restrict__ att, float* __restrict__ lnx, float* __restrict__ wv,
                         float* __restrict__ Ssum, int n){
  int lane = threadIdx.x & 63;
  int wid = (blockIdx.x<<2) + (threadIdx.x>>6);
  float gl=g[lane], bl=b[lane], al=att[lane];
  float scl=bsc[lane], shl=bsh[lane];
  float wacc=0.f;
  for(int node=wid; node<n; node+=4096){
    float raw = x[((size_t)node<<6)+lane];
    float v = fmaxf(fmaf(raw, scl, shl), 0.f);     // fused BN2 + relu
    float s=v;
    #pragma unroll
    for(int o=32;o>0;o>>=1) s += __shfl_xor(s,o);
    float mu = s*0.015625f;
    float d = v-mu;
    float q = d*d;
    #pragma unroll
    for(int o=32;o>0;o>>=1) q += __shfl_xor(q,o);
    float ln = d*rsqrtf(q*0.015625f + 1e-5f)*gl + bl;
    lnx[((size_t)node<<6)+lane] = ln;
    float a = ln*al;
    #pragma unroll
    for(int o=32;o>0;o>>=1) a += __shfl_xor(a,o);
    float wgt = expf(tanhf(a));
    if(lane==0) wv[node]=wgt;
    wacc += wgt;
  }
  __shared__ float sred[4];
  if(lane==0) sred[threadIdx.x>>6]=wacc;
  __syncthreads();
  if(threadIdx.x==0) atomicAdd(Ssum, sred[0]+sred[1]+sred[2]+sred[3]);
}

__global__ void k_pool(const float* __restrict__ lnx, const float* __restrict__ wv,
                       const int* __restrict__ batch, float* __restrict__ psum, int n){
  int lane = threadIdx.x & 63;
  int wave = threadIdx.x >> 6;
  int start = blockIdx.x*512 + wave*128;
  if(start >= n) return;
  int end = min(start+128, n);
  int cur = batch[start];
  float acc = 0.f;
  for(int i=start;i<end;i++){
    int bb = batch[i];
    if(bb != cur){ atomicAdd(&psum[cur*64+lane], acc); acc=0.f; cur=bb; }
    acc = fmaf(lnx[(size_t)i*64+lane], wv[i], acc);
  }
  atomicAdd(&psum[cur*64+lane], acc);
}

__global__ void k_mlp(const float* __restrict__ psum, const int* __restrict__ cnt,
                      const float* __restrict__ Ssum,
                      const float* __restrict__ M0W, const float* __restrict__ M0b,
                      const float* __restrict__ M1W, const float* __restrict__ M1b,
                      const float* __restrict__ M2W, const float* __restrict__ M2b,
                      float* __restrict__ out){
  int b = threadIdx.x;
  float S = Ssum[0];
  int cb = cnt[b]; if(cb<1) cb=1;
  float inv = 1.f/(S*(float)cb);
  float p[64];
  #pragma unroll
  for(int f=0;f<64;f++) p[f] = psum[b*64+f]*inv;
  float h1[32];
  #pragma unroll
  for(int j=0;j<32;j++){
    float a=M0b[j];
    #pragma unroll
    for(int f=0;f<64;f++) a = fmaf(p[f], M0W[f*32+j], a);
    h1[j]=fmaxf(a,0.f);
  }
  float h2[16];
  #pragma unroll
  for(int j=0;j<16;j++){
    float a=M1b[j];
    #pragma unroll
    for(int f=0;f<32;f++) a = fmaf(h1[f], M1W[f*16+j], a);
    h2[j]=fmaxf(a,0.f);
  }
  #pragma unroll
  for(int j=0;j<2;j++){
    float a=M2b[j];
    #pragma unroll
    for(int f=0;f<16;f++) a = fmaf(h2[f], M2W[f*2+j], a);
    out[b*2+j]=a;
  }
}

// ---------------- launch ----------------

extern "C" void kernel_launch(void* const* d_in, const int* in_sizes, int n_in,
                              void* d_out, int out_size, void* d_ws, size_t ws_size,
                              hipStream_t stream){
  const float* x   = (const float*)d_in[0];
  const int*   ei  = (const int*)d_in[1];
  const int* batch = (const int*)d_in[2];
  const float* W0=(const float*)d_in[3],  *b0=(const float*)d_in[4],  *g0=(const float*)d_in[5],  *be0=(const float*)d_in[6];
  const float* W1=(const float*)d_in[7],  *b1=(const float*)d_in[8],  *g1=(const float*)d_in[9],  *be1=(const float*)d_in[10];
  const float* W2=(const float*)d_in[11], *b2=(const float*)d_in[12], *g2=(const float*)d_in[13], *be2=(const float*)d_in[14];
  const float* ln_g=(const float*)d_in[15], *ln_b=(const float*)d_in[16], *att=(const float*)d_in[17];
  const float* M0W=(const float*)d_in[18], *M0b=(const float*)d_in[19];
  const float* M1W=(const float*)d_in[20], *M1b=(const float*)d_in[21];
  const float* M2W=(const float*)d_in[22], *M2b=(const float*)d_in[23];
  const int N = in_sizes[0]/128;
  const int E = in_sizes[1]/2;
  const int* srcv = ei;
  const int* dstv = ei + E;

  char* base = (char*)d_ws;
  size_t off = 0;
  auto alloc = [&](size_t bytes)->char*{ char* p = base+off; off = (off+bytes+255)&~(size_t)255; return p; };
  // zeroed region first
  int*   deg    = (int*)  alloc((size_t)N*4);
  int*   cnt    = (int*)  alloc(64*4);
  float* stats  = (float*)alloc(6*256*4);
  float* psum   = (float*)alloc(64*64*4);
  float* Ssum   = (float*)alloc(4);
  size_t zero_bytes = off;
  float* dinv   = (float*)alloc((size_t)N*4);
  int*   rowptr = (int*)  alloc(((size_t)N+1)*4);
  int*   cursor = (int*)  alloc((size_t)N*4);
  int*   bsum   = (int*)  alloc(128*4);
  float* bnsc   = (float*)alloc(3*256*4);
  float* bnsh   = (float*)alloc(3*256*4);
  unsigned short* Wh0 = (unsigned short*)alloc((size_t)128*256*2);
  unsigned short* Wl0 = (unsigned short*)alloc((size_t)128*256*2);
  unsigned short* Wh1 = (unsigned short*)alloc((size_t)256*128*2);
  unsigned short* Wl1 = (unsigned short*)alloc((size_t)256*128*2);
  unsigned short* Wh2 = (unsigned short*)alloc((size_t)128*64*2);
  unsigned short* Wl2 = (unsigned short*)alloc((size_t)128*64*2);
  int*   adj    = (int*)  alloc((size_t)E*4);
  float* P      = (float*)alloc((size_t)N*256*4);   // [N,256]
  float* R      = (float*)alloc((size_t)N*128*4);   // [N,128]
  float* Q      = (float*)alloc((size_t)N*128*4);   // [N,128]
  (void)ws_size; (void)n_in; (void)out_size;

  hipMemsetAsync(d_ws, 0, zero_bytes, stream);

  // graph structure + weight prep
  k_deg_hist  <<<1024,256,0,stream>>>(dstv, deg, E);
  k_batch_hist<<<256,256,0,stream>>>(batch, cnt, N);
  k_dinv      <<<(N+255)/256,256,0,stream>>>(deg, dinv, N);
  int nblk = (N+1023)/1024;
  k_scan1<<<nblk,256,0,stream>>>(deg, bsum, N);
  k_scan2<<<1,128,0,stream>>>(bsum, nblk, rowptr, N);
  k_scan3<<<nblk,256,0,stream>>>(deg, bsum, rowptr, cursor, N);
  k_csr_fill<<<(E+255)/256,256,0,stream>>>(srcv, dstv, cursor, adj, E);
  k_prep_w<<<(128*256+255)/256,256,0,stream>>>(W0, Wh0, Wl0, 128, 256);
  k_prep_w<<<(256*128+255)/256,256,0,stream>>>(W1, Wh1, Wl1, 256, 128);
  k_prep_w<<<(128*64 +255)/256,256,0,stream>>>(W2, Wh2, Wl2, 128, 64);

  const int gemm_grid = (N+127)/128;

  // ---- layer 0: R = agg(x*dinv); P = R@W0 + b0; stats ----
  k_aggregate<true><<<(N*32+255)/256,256,0,stream>>>(x, rowptr, adj, dinv, nullptr, R, N, 5);
  k_gemm_mfma<128,256,false,true,false><<<gemm_grid,256,0,stream>>>(R, Wh0, Wl0, nullptr,nullptr, b0, nullptr, P, N);
  k_bn_stats <<<256,256,0,stream>>>(P, stats+0, stats+256, N, 8);
  k_bn_finalize<<<1,256,0,stream>>>(stats+0, stats+256, g0, be0, bnsc+0, bnsh+0, N, 256);

  // ---- layer 1: Q = relu(bn0(P))@W1 * dinv; R = agg(Q) + b1; stats ----
  k_gemm_mfma<256,128,true,false,true><<<gemm_grid,256,0,stream>>>(P, Wh1, Wl1, bnsc+0, bnsh+0, nullptr, dinv, Q, N);
  k_aggregate<false><<<(N*32+255)/256,256,0,stream>>>(Q, rowptr, adj, dinv, b1, R, N, 5);
  k_bn_stats <<<256,256,0,stream>>>(R, stats+512, stats+768, N, 7);
  k_bn_finalize<<<1,256,0,stream>>>(stats+512, stats+768, g1, be1, bnsc+256, bnsh+256, N, 128);

  // ---- layer 2: Q = relu(bn1(R))@W2 * dinv; P = agg(Q) + b2; stats ----
  k_gemm_mfma<128,64,true,false,true><<<gemm_grid,256,0,stream>>>(R, Wh2, Wl2, bnsc+256, bnsh+256, nullptr, dinv, Q, N);
  k_aggregate<false><<<(N*16+255)/256,256,0,stream>>>(Q, rowptr, adj, dinv, b2, P, N, 4);
  k_bn_stats <<<256,256,0,stream>>>(P, stats+1024, stats+1280, N, 6);
  k_bn_finalize<<<1,256,0,stream>>>(stats+1024, stats+1280, g2, be2, bnsc+512, bnsh+512, N, 64);

  // ---- head (BN2+relu fused into ln_att) ----
  k_ln_att<<<1024,256,0,stream>>>(P, bnsc+512, bnsh+512, ln_g, ln_b, att, Q, R, Ssum, N);
  k_pool  <<<(N+511)/512,256,0,stream>>>(Q, R, batch, psum, N);
  k_mlp   <<<1,64,0,stream>>>(psum, cnt, Ssum, M0W,M0b,M1W,M1b,M2W,M2b, (float*)d_out);
}